// Round 6
// baseline (490.207 us; speedup 1.0000x reference)
//
#include <hip/hip_runtime.h>
#include <hip/hip_bf16.h>
#include <math.h>

#define HEADS 4
#define HID 48
#define FDIM 192   // HEADS*HID
#define NEG_SLOPE 0.2f

typedef float f4 __attribute__((ext_vector_type(4)));

// ---------------------------------------------------------------------------
// DPP helpers (VALU-pipe cross-lane, 16-lane row based).
template<int CTRL>
__device__ __forceinline__ float dpp_add(float v) {
    int t = __builtin_amdgcn_update_dpp(0, __float_as_int(v), CTRL, 0xF, 0xF, true);
    return v + __int_as_float(t);
}
template<int CTRL>
__device__ __forceinline__ float dpp_max(float v) {
    int t = __builtin_amdgcn_update_dpp(0, __float_as_int(v), CTRL, 0xF, 0xF, true);
    return fmaxf(v, __int_as_float(t));
}
// sum over the 4 lanes of a quad (cq axis): quad_perm xor1 + xor2
__device__ __forceinline__ float red_cq(float v) {
    v = dpp_add<0xB1>(v);
    v = dpp_add<0x4E>(v);
    return v;
}
// sum over stride-4 lanes within a 16-lane row (es axis): row_ror:4 + row_ror:8
__device__ __forceinline__ float red_es(float v) {
    v = dpp_add<0x124>(v);
    v = dpp_add<0x128>(v);
    return v;
}
__device__ __forceinline__ float rowmax16(float v) {
    v = dpp_max<0x124>(v);
    v = dpp_max<0x128>(v);
    return v;   // max over the 16-lane row (scores already cq-uniform)
}

// Per-wave int64-vs-int32 detection: odd 32-bit words of first 64 entries all
// zero -> int64. Deterministic, identical in every wave.
__device__ __forceinline__ int detect64(const int* __restrict__ ei) {
    int l = (int)(threadIdx.x & 63);
    int v = ei[2 * l + 1];
    return (__ballot(v != 0) == 0ULL) ? 1 : 0;
}

// ---------------------------------------------------------------------------
// Histogram of destination nodes (including self-loops e in [E, E+N)).
__global__ void hist_kernel(const int* __restrict__ ei,
                            int* __restrict__ deg, int E, int E2) {
    int is64 = detect64(ei);
    for (int e = blockIdx.x * blockDim.x + threadIdx.x; e < E2;
         e += gridDim.x * blockDim.x) {
        int d;
        if (e < E) d = is64 ? ei[2 * (E + e)] : ei[E + e];
        else       d = e - E;
        atomicAdd(&deg[d], 1);
    }
}

// ---------------------------------------------------------------------------
// Hierarchical scan: (A) per-block inclusive scan + block sums,
// (B) single-block exclusive scan of block sums, (C) add offsets -> rowptr
//     (also zeroes the scatter cursor, saving a memset dispatch).
__global__ void scan_local_kernel(const int* __restrict__ deg, int* __restrict__ incl,
                                  int* __restrict__ bsum, int N) {
    __shared__ int sm[256];
    int i = blockIdx.x * 256 + threadIdx.x;
    int v = (i < N) ? deg[i] : 0;
    sm[threadIdx.x] = v;
    __syncthreads();
    #pragma unroll
    for (int off = 1; off < 256; off <<= 1) {
        int t = ((int)threadIdx.x >= off) ? sm[threadIdx.x - off] : 0;
        __syncthreads();
        sm[threadIdx.x] += t;
        __syncthreads();
    }
    if (i < N) incl[i] = sm[threadIdx.x];
    if (threadIdx.x == 255) bsum[blockIdx.x] = sm[255];
}

__global__ void scan_bsum_kernel(int* __restrict__ bsum, int nb) {
    __shared__ int sm[256];
    __shared__ int running;
    if (threadIdx.x == 0) running = 0;
    __syncthreads();
    for (int base = 0; base < nb; base += 256) {
        int i = base + (int)threadIdx.x;
        int v = (i < nb) ? bsum[i] : 0;
        sm[threadIdx.x] = v;
        __syncthreads();
        #pragma unroll
        for (int off = 1; off < 256; off <<= 1) {
            int t = ((int)threadIdx.x >= off) ? sm[threadIdx.x - off] : 0;
            __syncthreads();
            sm[threadIdx.x] += t;
            __syncthreads();
        }
        if (i < nb) bsum[i] = running + sm[threadIdx.x] - v;   // exclusive
        __syncthreads();
        if (threadIdx.x == 0) running += sm[255];
        __syncthreads();
    }
}

__global__ void scan_final_kernel(const int* __restrict__ incl, const int* __restrict__ bsum,
                                  int* __restrict__ rowptr, int* __restrict__ cursor, int N) {
    int i = blockIdx.x * 256 + threadIdx.x;
    if (i < N) { rowptr[i + 1] = incl[i] + bsum[blockIdx.x]; cursor[i] = 0; }
    if (i == 0) rowptr[0] = 0;
}

// ---------------------------------------------------------------------------
// Scatter edges into CSR order (sorted by dst). cursor zeroed by scan_final.
__global__ void scatter_kernel(const int* __restrict__ ei,
                               const int* __restrict__ rowptr, int* __restrict__ cursor,
                               int* __restrict__ srcs, int E, int E2) {
    int is64 = detect64(ei);
    for (int e = blockIdx.x * blockDim.x + threadIdx.x; e < E2;
         e += gridDim.x * blockDim.x) {
        int s, d;
        if (e < E) {
            if (is64) { s = ei[2 * e]; d = ei[2 * (E + e)]; }
            else      { s = ei[e];     d = ei[E + e]; }
        } else {
            s = d = e - E;
        }
        int pos = rowptr[d] + atomicAdd(&cursor[d], 1);
        srcs[pos] = s;
    }
}

// ---------------------------------------------------------------------------
// Dual GEMM, register-tiled: xl = xin@Wl + bl, xr = xin@Wr + br.
template<int DIN>
__global__ __launch_bounds__(192) void gemm2t_kernel(
    const float* __restrict__ xin,
    const float* __restrict__ Wl, const float* __restrict__ bl,
    const float* __restrict__ Wr, const float* __restrict__ br,
    float* __restrict__ xl, float* __restrict__ xr, int N) {
    int t  = (int)threadIdx.x;
    int cg = t % 48;           // column group -> cols c0..c0+3
    int ng = t / 48;           // node group 0..3
    int c0 = cg * 4;
    int n0 = blockIdx.x * 16 + ng * 4;
    if (n0 >= N) return;

    f4 bLv = *(const f4*)&bl[c0];
    f4 bRv = *(const f4*)&br[c0];
    f4 accL[4], accR[4];
    #pragma unroll
    for (int i = 0; i < 4; ++i) { accL[i] = bLv; accR[i] = bRv; }

    if (n0 + 3 < N) {
        if (DIN == 3) {
            float xv[4][3];
            #pragma unroll
            for (int i = 0; i < 4; ++i) {
                const float* xp = xin + (size_t)(n0 + i) * 3;
                xv[i][0] = xp[0]; xv[i][1] = xp[1]; xv[i][2] = xp[2];
            }
            #pragma unroll
            for (int k = 0; k < 3; ++k) {
                f4 wl4 = *(const f4*)&Wl[k * FDIM + c0];
                f4 wr4 = *(const f4*)&Wr[k * FDIM + c0];
                #pragma unroll
                for (int i = 0; i < 4; ++i) {
                    float xs = xv[i][k];
                    accL[i] += xs * wl4;
                    accR[i] += xs * wr4;
                }
            }
        } else {
            #pragma unroll
            for (int kk = 0; kk < DIN; kk += 8) {
                float xv[4][8];
                #pragma unroll
                for (int i = 0; i < 4; ++i) {
                    const float* xp = xin + (size_t)(n0 + i) * DIN + kk;
                    f4 xa = *(const f4*)xp;
                    f4 xb = *(const f4*)(xp + 4);
                    #pragma unroll
                    for (int q = 0; q < 4; ++q) { xv[i][q] = xa[q]; xv[i][4 + q] = xb[q]; }
                }
                #pragma unroll
                for (int k = 0; k < 8; ++k) {
                    f4 wl4 = *(const f4*)&Wl[(kk + k) * FDIM + c0];
                    f4 wr4 = *(const f4*)&Wr[(kk + k) * FDIM + c0];
                    #pragma unroll
                    for (int i = 0; i < 4; ++i) {
                        float xs = xv[i][k];
                        accL[i] += xs * wl4;
                        accR[i] += xs * wr4;
                    }
                }
            }
        }
        #pragma unroll
        for (int i = 0; i < 4; ++i) {
            *(f4*)&xl[(size_t)(n0 + i) * FDIM + c0] = accL[i];
            *(f4*)&xr[(size_t)(n0 + i) * FDIM + c0] = accR[i];
        }
    } else {
        for (int i = 0; i < 4; ++i) {
            int n = n0 + i;
            if (n >= N) break;
            f4 aL = bLv;
            f4 aR = bRv;
            for (int k = 0; k < DIN; ++k) {
                float xs = xin[(size_t)n * DIN + k];
                f4 wl4 = *(const f4*)&Wl[k * FDIM + c0];
                f4 wr4 = *(const f4*)&Wr[k * FDIM + c0];
                aL += xs * wl4;
                aR += xs * wr4;
            }
            *(f4*)&xl[(size_t)n * FDIM + c0] = aL;
            *(f4*)&xr[(size_t)n * FDIM + c0] = aR;
        }
    }
}

// ---------------------------------------------------------------------------
// Merged GATv2 layer, (head, edge-slot, channel-quarter) lane map:
//   lane = h*16 + es*4 + cq ; lane owns 12 CONTIGUOUS channels [cq*12, cq*12+12)
//   of head h for edge-slot es. Gathers are 3x dwordx4 per lane (vs 12x dword),
//   score reduce = 2 DPP (quad), es-combination deferred to 2 DPP at loop end,
//   1 exp per 4 edges per lane. 8 edges per iteration (2 independent score sets).
#define SCORE_MASKED (-1e38f)
#define M_INIT       (-3e38f)
#define DEFER_THR    8.0f

__global__ __launch_bounds__(256) void gat_layer_kernel(
    const float* __restrict__ xl, const float* __restrict__ xr,
    const float* __restrict__ att, const float* __restrict__ bias,
    const int* __restrict__ rowptr, const int* __restrict__ srcs,
    float* __restrict__ xout,                       // [N,48] (non-final)
    float* __restrict__ out,                        // [N]    (final)
    const float* __restrict__ head_w, const float* __restrict__ head_b,
    int N, int final_flag) {
    int wave = (int)((blockIdx.x * blockDim.x + threadIdx.x) >> 6);
    wave = __builtin_amdgcn_readfirstlane(wave);   // force SGPR: uniform bases
    if (wave >= N) return;
    int lane = (int)(threadIdx.x & 63);
    int n  = wave;
    int h  = lane >> 4;          // head
    int es = (lane >> 2) & 3;    // edge slot
    int cq = lane & 3;           // channel quarter (12 channels)
    int j0 = h * HID + cq * 12;  // flat channel-block start in [192]

    const float* xrp = xr + (size_t)n * FDIM + j0;
    f4 r0 = *(const f4*)xrp;
    f4 r1 = *(const f4*)(xrp + 4);
    f4 r2 = *(const f4*)(xrp + 8);
    f4 a0 = *(const f4*)&att[j0];
    f4 a1 = *(const f4*)&att[j0 + 4];
    f4 a2 = *(const f4*)&att[j0 + 8];

    float m = M_INIT, dn = 0.f;
    f4 acc0 = {0.f, 0.f, 0.f, 0.f}, acc1 = acc0, acc2 = acc0;

    int e0 = rowptr[n], e1 = rowptr[n + 1];
    int elast = e1 - 1;

    for (int e = e0; e < e1; e += 8) {
        int iA = e + es;
        int iB = e + 4 + es;
        int kA = (iA < e1) ? iA : elast;
        int kB = (iB < e1) ? iB : elast;
        int sA = srcs[kA];
        int sB = srcs[kB];
        const float* pA = xl + (size_t)sA * FDIM + j0;
        const float* pB = xl + (size_t)sB * FDIM + j0;
        f4 A0 = *(const f4*)pA, A1 = *(const f4*)(pA + 4), A2 = *(const f4*)(pA + 8);
        f4 B0 = *(const f4*)pB, B1 = *(const f4*)(pB + 4), B2 = *(const f4*)(pB + 8);

        float scA = 0.f, scB = 0.f;
        #pragma unroll
        for (int q = 0; q < 4; ++q) {
            float t, u;
            t = A0[q] + r0[q]; u = fmaf(NEG_SLOPE, fminf(t, 0.f), fmaxf(t, 0.f)); scA = fmaf(u, a0[q], scA);
            t = A1[q] + r1[q]; u = fmaf(NEG_SLOPE, fminf(t, 0.f), fmaxf(t, 0.f)); scA = fmaf(u, a1[q], scA);
            t = A2[q] + r2[q]; u = fmaf(NEG_SLOPE, fminf(t, 0.f), fmaxf(t, 0.f)); scA = fmaf(u, a2[q], scA);
            t = B0[q] + r0[q]; u = fmaf(NEG_SLOPE, fminf(t, 0.f), fmaxf(t, 0.f)); scB = fmaf(u, a0[q], scB);
            t = B1[q] + r1[q]; u = fmaf(NEG_SLOPE, fminf(t, 0.f), fmaxf(t, 0.f)); scB = fmaf(u, a1[q], scB);
            t = B2[q] + r2[q]; u = fmaf(NEG_SLOPE, fminf(t, 0.f), fmaxf(t, 0.f)); scB = fmaf(u, a2[q], scB);
        }
        scA = red_cq(scA);                       // full 48-ch dot for (h, esA)
        scB = red_cq(scB);
        scA = (iA < e1) ? scA : SCORE_MASKED;
        scB = (iB < e1) ? scB : SCORE_MASKED;

        float bmax = rowmax16(fmaxf(scA, scB));  // max over the 8 edges, per head
        if (__any(bmax > m + DEFER_THR)) {       // rare after first batch
            float nm = fmaxf(m, bmax);
            float sc_ = __expf(m - nm);          // m=M_INIT -> 0
            dn *= sc_; acc0 *= sc_; acc1 *= sc_; acc2 *= sc_;
            m = nm;
        }
        float qA = __expf(scA - m);              // masked -> exp(-huge) = 0
        float qB = __expf(scB - m);
        dn += qA + qB;
        acc0 += qA * A0 + qB * B0;
        acc1 += qA * A1 + qB * B1;
        acc2 += qA * A2 + qB * B2;
    }

    // combine the 4 edge slots (stride-4 lanes within the 16-lane row)
    dn = red_es(dn);
    #pragma unroll
    for (int q = 0; q < 4; ++q) {
        acc0[q] = red_es(acc0[q]);
        acc1[q] = red_es(acc1[q]);
        acc2[q] = red_es(acc2[q]);
    }

    float inv = 1.0f / (dn + 1e-16f);
    f4 o0 = acc0 * inv, o1 = acc1 * inv, o2 = acc2 * inv;

    // mean over heads: sum across the 4 head rows (lane^16, lane^32)
    #pragma unroll
    for (int q = 0; q < 4; ++q) {
        float v;
        v = o0[q]; v += __shfl_xor(v, 16); v += __shfl_xor(v, 32); o0[q] = v;
        v = o1[q]; v += __shfl_xor(v, 16); v += __shfl_xor(v, 32); o1[q] = v;
        v = o2[q]; v += __shfl_xor(v, 16); v += __shfl_xor(v, 32); o2[q] = v;
    }
    int c0 = cq * 12;
    f4 b0v = *(const f4*)&bias[c0];
    f4 b1v = *(const f4*)&bias[c0 + 4];
    f4 b2v = *(const f4*)&bias[c0 + 8];
    o0 = 0.25f * o0 + b0v;
    o1 = 0.25f * o1 + b1v;
    o2 = 0.25f * o2 + b2v;
    // ELU via exp(x)-1 (abs error ~1e-7, fast trans pipe)
    #pragma unroll
    for (int q = 0; q < 4; ++q) {
        o0[q] = (o0[q] > 0.f) ? o0[q] : (__expf(o0[q]) - 1.f);
        o1[q] = (o1[q] > 0.f) ? o1[q] : (__expf(o1[q]) - 1.f);
        o2[q] = (o2[q] > 0.f) ? o2[q] : (__expf(o2[q]) - 1.f);
    }

    if (!final_flag) {
        if (h == 0 && es == 0) {                 // 4 lanes write 12 floats each
            float* xo = xout + (size_t)n * HID + c0;
            *(f4*)xo = o0;
            *(f4*)(xo + 4) = o1;
            *(f4*)(xo + 8) = o2;
        }
    } else {
        f4 w0 = *(const f4*)&head_w[c0];
        f4 w1 = *(const f4*)&head_w[c0 + 4];
        f4 w2 = *(const f4*)&head_w[c0 + 8];
        float part = 0.f;
        #pragma unroll
        for (int q = 0; q < 4; ++q)
            part += o0[q] * w0[q] + o1[q] * w1[q] + o2[q] * w2[q];
        part = red_cq(part);                     // full 48-ch dot
        if (lane == 0) {
            float v = part + head_b[0];
            out[n] = (v > 0.f) ? v : 0.f;
        }
    }
}

// ---------------------------------------------------------------------------
extern "C" void kernel_launch(void* const* d_in, const int* in_sizes, int n_in,
                              void* d_out, int out_size, void* d_ws, size_t ws_size,
                              hipStream_t stream) {
    const float* x0 = (const float*)d_in[0];
    const int*   ei = (const int*)d_in[1];

    const int N  = in_sizes[0] / 3;        // 50000
    const int E  = in_sizes[1] / 2;        // 800000
    const int E2 = E + N;                  // edges incl. self-loops

    const float* Wl[3];  const float* bl[3];
    const float* Wr[3];  const float* br[3];
    const float* att[3]; const float* bias[3];
    for (int li = 0; li < 3; ++li) {
        int b = 2 + 6 * li;
        Wl[li]   = (const float*)d_in[b + 0];
        bl[li]   = (const float*)d_in[b + 1];
        Wr[li]   = (const float*)d_in[b + 2];
        br[li]   = (const float*)d_in[b + 3];
        att[li]  = (const float*)d_in[b + 4];
        bias[li] = (const float*)d_in[b + 5];
    }
    const float* head_w = (const float*)d_in[20];
    const float* head_b = (const float*)d_in[21];
    float* out = (float*)d_out;

    // ---- workspace carve-up (256B aligned) ----
    size_t off = 0;
    auto alloc = [&](size_t bytes) -> void* {
        void* p = (char*)d_ws + off;
        off = (off + bytes + 255) & ~(size_t)255;
        return p;
    };
    const int nb = (N + 255) / 256;
    int*   deg    = (int*)alloc((size_t)N * sizeof(int));        // reused as cursor
    int*   incl   = (int*)alloc((size_t)N * sizeof(int));
    int*   bsum   = (int*)alloc((size_t)nb * sizeof(int));
    int*   rowptr = (int*)alloc((size_t)(N + 1) * sizeof(int));
    int*   srcs   = (int*)alloc((size_t)E2 * sizeof(int));
    float* xlb    = (float*)alloc((size_t)N * FDIM * sizeof(float));
    float* xrb    = (float*)alloc((size_t)N * FDIM * sizeof(float));
    float* xbuf   = (float*)alloc((size_t)N * HID * sizeof(float));
    (void)ws_size;

    // ---- build CSR (layer-invariant) ----
    (void)hipMemsetAsync(deg, 0, (size_t)N * sizeof(int), stream);
    hist_kernel<<<2048, 256, 0, stream>>>(ei, deg, E, E2);
    scan_local_kernel<<<nb, 256, 0, stream>>>(deg, incl, bsum, N);
    scan_bsum_kernel<<<1, 256, 0, stream>>>(bsum, nb);
    scan_final_kernel<<<nb, 256, 0, stream>>>(incl, bsum, rowptr, deg, N);
    scatter_kernel<<<2048, 256, 0, stream>>>(ei, rowptr, deg, srcs, E, E2);

    const int waves_per_block = 4;  // 256 threads
    int gat_blocks = (N + waves_per_block - 1) / waves_per_block;
    int gemm_blocks = (N + 15) / 16;

    // ---- layer 0 (din=3) ----
    gemm2t_kernel<3><<<gemm_blocks, 192, 0, stream>>>(x0, Wl[0], bl[0], Wr[0], br[0], xlb, xrb, N);
    gat_layer_kernel<<<gat_blocks, 256, 0, stream>>>(xlb, xrb, att[0], bias[0],
        rowptr, srcs, xbuf, nullptr, nullptr, nullptr, N, 0);

    // ---- layer 1 (din=48) ----
    gemm2t_kernel<HID><<<gemm_blocks, 192, 0, stream>>>(xbuf, Wl[1], bl[1], Wr[1], br[1], xlb, xrb, N);
    gat_layer_kernel<<<gat_blocks, 256, 0, stream>>>(xlb, xrb, att[1], bias[1],
        rowptr, srcs, xbuf, nullptr, nullptr, nullptr, N, 0);

    // ---- layer 2 (din=48) + fused head MLP + ReLU ----
    gemm2t_kernel<HID><<<gemm_blocks, 192, 0, stream>>>(xbuf, Wl[2], bl[2], Wr[2], br[2], xlb, xrb, N);
    gat_layer_kernel<<<gat_blocks, 256, 0, stream>>>(xlb, xrb, att[2], bias[2],
        rowptr, srcs, nullptr, out, head_w, head_b, N, 1);

    (void)n_in; (void)out_size;
}